// Round 22
// baseline (2555.824 us; speedup 1.0000x reference)
//
#include <hip/hip_runtime.h>
#include <hip/hip_bf16.h>

#define D_DIM 3072
#define NTRAIN 16384
#define NTEST 8192

typedef __attribute__((ext_vector_type(4))) float f32x4;
typedef __attribute__((ext_vector_type(4))) int i32x4;
typedef __attribute__((ext_vector_type(8))) int i32x8;

__device__ __forceinline__ unsigned short f2bf(float f) {
  union { float f; unsigned u; } x; x.f = f;
  unsigned r = x.u + 0x7FFFu + ((x.u >> 16) & 1u);
  return (unsigned short)(r >> 16);
}

__device__ __forceinline__ float bf2f(unsigned short b) {
  union { unsigned u; float f; } x; x.u = ((unsigned)b) << 16;
  return x.f;
}

__device__ __forceinline__ i32x8 cmb(i32x4 lo, i32x4 hi) {
  i32x8 r;
  r[0] = lo[0]; r[1] = lo[1]; r[2] = lo[2]; r[3] = lo[3];
  r[4] = hi[0]; r[5] = hi[1]; r[6] = hi[2]; r[7] = hi[3];
  return r;
}

__device__ __forceinline__ void gload16(const void* g, void* l) {
  __builtin_amdgcn_global_load_lds(
      (const __attribute__((address_space(1))) void*)g,
      (__attribute__((address_space(3))) void*)l, 16, 0, 0);
}

// T1a: bijective chunked XCD swizzle + 8x8 supertile (needs gx%8==0, gy%8==0).
__device__ __forceinline__ void swz_tile(int& tileY, int& tileX) {
  const int gx = gridDim.x, gy = gridDim.y;
  const int L = blockIdx.y * gx + blockIdx.x;
  const int q = (gx * gy) >> 3;
  const int s = (L & 7) * q + (L >> 3);
  const int sid = s >> 6;
  const int t = s & 63;
  const int scols = gx >> 3;
  const int sy = sid / scols, sx = sid - sy * scols;
  tileY = sy * 8 + (t >> 3);
  tileX = sx * 8 + (t & 7);
}

// T1b: plain bijective chunked swizzle (needs nwg%8==0 only).
__device__ __forceinline__ void swz_lin(int& tileY, int& tileX) {
  const int gx = gridDim.x;
  const int nwg = gx * gridDim.y;
  const int L = blockIdx.y * gx + blockIdx.x;
  const int s = (L & 7) * (nwg >> 3) + (L >> 3);
  tileY = s / gx;
  tileX = s - tileY * gx;
}

// ---------------- pass 0 ----------------
__global__ void k_convert8(const float* __restrict__ in, unsigned char* __restrict__ out, long n8) {
  long i = (long)blockIdx.x * blockDim.x + threadIdx.x;
  long stride = (long)gridDim.x * blockDim.x;
  for (; i < n8; i += stride) {
    float4 a = reinterpret_cast<const float4*>(in)[i * 2];
    float4 b = reinterpret_cast<const float4*>(in)[i * 2 + 1];
    int w0 = __builtin_amdgcn_cvt_pk_fp8_f32(a.x, a.y, 0, false);
    w0 = __builtin_amdgcn_cvt_pk_fp8_f32(a.z, a.w, w0, true);
    int w1 = __builtin_amdgcn_cvt_pk_fp8_f32(b.x, b.y, 0, false);
    w1 = __builtin_amdgcn_cvt_pk_fp8_f32(b.z, b.w, w1, true);
    reinterpret_cast<int2*>(out)[i] = make_int2(w0, w1);
  }
}

__global__ void k_copy4(const float4* __restrict__ in, float4* __restrict__ out, long n4) {
  long i = (long)blockIdx.x * blockDim.x + threadIdx.x;
  long stride = (long)gridDim.x * blockDim.x;
  for (; i < n4; i += stride) out[i] = in[i];
}

// Mt8[n][k] = fp8(M[k][n])
__global__ void k_transpose_fp8(const float* __restrict__ M, unsigned char* __restrict__ Mt) {
  __shared__ float t[32][33];
  int bx = blockIdx.x * 32, by = blockIdx.y * 32;
  int tx = threadIdx.x, ty = threadIdx.y;
#pragma unroll
  for (int i = 0; i < 32; i += 8)
    t[ty + i][tx] = M[(size_t)(by + ty + i) * D_DIM + bx + tx];
  __syncthreads();
#pragma unroll
  for (int i = 0; i < 32; i += 8) {
    float v = t[tx][ty + i];
    int p = __builtin_amdgcn_cvt_pk_fp8_f32(v, v, 0, false);
    Mt[(size_t)(bx + ty + i) * D_DIM + by + tx] = (unsigned char)(p & 0xFF);
  }
}

// ======== shared MX-fp8 mainloop: 256x256 tile, BK=128, B direct-from-global ========
// 8 waves (2M x 4N), wave tile 128x64, acc[8][4]=128 regs. A-only LDS (64 KiB dbuf,
// 0-conflict XOR layout); B operands load global->VGPR (rows 128B-aligned at k0:
// each 16-row pair = 16 full cache lines, L2-resident panels), depth-1 prefetched
// into ping-pong regs (parity-unrolled; static indexing). Cuts LDS unit load ~40%
// (the R17-R21 non-MFMA pole); B traffic rides the vmem/L2 pipe instead.
// mfma_scale_f32_16x16x128_f8f6f4, unit scales (E8M0=127) = exact fp8 math at 2x.
// One sync per tile: vmcnt(0) covers A-stage AND B-reg loads; s_barrier.
__device__ __forceinline__ void mainloopBG(const unsigned char* __restrict__ ga,
                                           const unsigned char* __restrict__ gB,
                                           unsigned char* As,
                                           int aRow0, int bAbs0, int lhi, int tid,
                                           f32x4 acc[8][4]) {
  const int nt = D_DIM / 128;                    // 24
  const int g0 = lhi, g1 = lhi ^ 4;
  const unsigned char* pB0 = gB + (size_t)(bAbs0)*D_DIM;
  const unsigned char* pB1 = gB + (size_t)(bAbs0 + 16) * D_DIM;
  const unsigned char* pB2 = gB + (size_t)(bAbs0 + 32) * D_DIM;
  const unsigned char* pB3 = gB + (size_t)(bAbs0 + 48) * D_DIM;
  // prologue: stage A(0); load B(0) -> bA
#pragma unroll
  for (int j = 0; j < 4; ++j)
    gload16(ga + (size_t)j * 64 * D_DIM, As + j * 8192 + tid * 16);
  i32x8 bA[4], bB[4];
  bA[0] = cmb(*(const i32x4*)(pB0 + g0 * 16), *(const i32x4*)(pB0 + g1 * 16));
  bA[1] = cmb(*(const i32x4*)(pB1 + g0 * 16), *(const i32x4*)(pB1 + g1 * 16));
  bA[2] = cmb(*(const i32x4*)(pB2 + g0 * 16), *(const i32x4*)(pB2 + g1 * 16));
  bA[3] = cmb(*(const i32x4*)(pB3 + g0 * 16), *(const i32x4*)(pB3 + g1 * 16));

#define RDA(Ac, q, H)                                                                \
  cmb(*reinterpret_cast<const i32x4*>(                                               \
          &(Ac)[(aRow0 + (q) * 32 + (H) * 16) * 128 +                                \
                ((g0 ^ ((aRow0 + (q) * 32 + (H) * 16) & 7)) * 16)]),                 \
      *reinterpret_cast<const i32x4*>(                                               \
          &(Ac)[(aRow0 + (q) * 32 + (H) * 16) * 128 +                                \
                ((g1 ^ ((aRow0 + (q) * 32 + (H) * 16) & 7)) * 16)]))

#define TILEBODY(par, bNow, bNxt)                                                    \
  {                                                                                  \
    const int t = tt + (par);                                                        \
    const unsigned char* Ac = As + (par) * 32768;                                    \
    unsigned char* An = As + ((par) ^ 1) * 32768;                                    \
    asm volatile("s_waitcnt vmcnt(0)" ::: "memory");                                 \
    __builtin_amdgcn_s_barrier();                                                    \
    __builtin_amdgcn_sched_barrier(0);                                               \
    if (t + 1 < nt) {                                                                \
      const int k1 = (t + 1) * 128;                                                  \
      _Pragma("unroll") for (int j = 0; j < 4; ++j)                                  \
        gload16(ga + (size_t)j * 64 * D_DIM + k1, An + j * 8192 + tid * 16);         \
      bNxt[0] = cmb(*(const i32x4*)(pB0 + k1 + g0 * 16), *(const i32x4*)(pB0 + k1 + g1 * 16)); \
      bNxt[1] = cmb(*(const i32x4*)(pB1 + k1 + g0 * 16), *(const i32x4*)(pB1 + k1 + g1 * 16)); \
      bNxt[2] = cmb(*(const i32x4*)(pB2 + k1 + g0 * 16), *(const i32x4*)(pB2 + k1 + g1 * 16)); \
      bNxt[3] = cmb(*(const i32x4*)(pB3 + k1 + g0 * 16), *(const i32x4*)(pB3 + k1 + g1 * 16)); \
    }                                                                                \
    __builtin_amdgcn_sched_barrier(0);                                               \
    _Pragma("unroll") for (int q = 0; q < 4; ++q) {                                  \
      i32x8 a0 = RDA(Ac, q, 0), a1 = RDA(Ac, q, 1);                                  \
      __builtin_amdgcn_s_setprio(1);                                                 \
      _Pragma("unroll") for (int n = 0; n < 4; ++n) {                                \
        acc[q * 2][n] = __builtin_amdgcn_mfma_scale_f32_16x16x128_f8f6f4(            \
            a0, bNow[n], acc[q * 2][n], 0, 0, 0, 127, 0, 127);                       \
        acc[q * 2 + 1][n] = __builtin_amdgcn_mfma_scale_f32_16x16x128_f8f6f4(        \
            a1, bNow[n], acc[q * 2 + 1][n], 0, 0, 0, 127, 0, 127);                   \
      }                                                                              \
      __builtin_amdgcn_s_setprio(0);                                                 \
      __builtin_amdgcn_sched_barrier(0);                                             \
    }                                                                                \
  }

  for (int tt = 0; tt < nt; tt += 2) {
    TILEBODY(0, bA, bB)
    TILEBODY(1, bB, bA)
  }
#undef TILEBODY
#undef RDA
}

// ---- GEMM1: X @ M, MX-fp8. Epilogue: norm2 dot vs f32 X (+ optional sM8) ----
template <bool WRITE_SM>
__global__ __launch_bounds__(512, 2) void k_gemm_xm8(const unsigned char* __restrict__ X8,
                                                     const unsigned char* __restrict__ Mt8,
                                                     const float* __restrict__ Xf,
                                                     unsigned char* __restrict__ smOut,
                                                     float* __restrict__ norm) {
  __shared__ unsigned char As[2 * 256 * 128];    // 64 KiB, A only
  const int tid = threadIdx.x, lane = tid & 63, wave = tid >> 6;
  const int wm = wave >> 2, wn = wave & 3;       // 2M x 4N
  const int l15 = lane & 15, lhi = lane >> 4;
  int tileY, tileX;
  swz_lin(tileY, tileX);
  const int rowBase = tileY * 256, colBase = tileX * 256;
  const int srow = tid >> 3, ssl = tid & 7;
  const unsigned char* ga = X8 + (size_t)(rowBase + srow) * D_DIM + ((ssl ^ (srow & 7)) * 16);
  f32x4 acc[8][4] = {};
  mainloopBG(ga, Mt8, As, wm * 128 + l15, colBase + wn * 64 + l15, lhi, tid, acc);
  __syncthreads();

  const int c0 = colBase + wn * 64 + l15;
#pragma unroll
  for (int m = 0; m < 8; ++m) {
#pragma unroll
    for (int r = 0; r < 4; ++r) {
      const size_t grow = rowBase + wm * 128 + m * 16 + lhi * 4 + r;
      float v = 0.f;
#pragma unroll
      for (int n = 0; n < 4; ++n) {
        float a = acc[m][n][r];
        const int gcol = c0 + n * 16;
        v += a * Xf[grow * D_DIM + gcol];
        if (WRITE_SM) {
          int pk = __builtin_amdgcn_cvt_pk_fp8_f32(a, a, 0, false);
          smOut[grow * D_DIM + gcol] = (unsigned char)(pk & 0xFF);
        }
      }
      v += __shfl_xor(v, 1); v += __shfl_xor(v, 2);
      v += __shfl_xor(v, 4); v += __shfl_xor(v, 8);
      if ((lane & 15) == 0) atomicAdd(&norm[grow], v);
    }
  }
}

// ---- GEMM2: MX-fp8, STORE-ONLY epilogue -> bf16 S half ----
__global__ __launch_bounds__(512, 2) void k_gemm_cross(const unsigned char* __restrict__ sM8,
                                                       const unsigned char* __restrict__ xte8h,
                                                       const float* __restrict__ sn2,
                                                       const float* __restrict__ cn2h,
                                                       unsigned short* __restrict__ S) {
  __shared__ unsigned char As[2 * 256 * 128];    // 64 KiB, A only
  const int tid = threadIdx.x, lane = tid & 63, wave = tid >> 6;
  const int wm = wave >> 2, wn = wave & 3;
  const int l15 = lane & 15, lhi = lane >> 4;
  int tileY, tileX;
  swz_tile(tileY, tileX);
  const int rowBase = tileY * 256, colBase = tileX * 256;
  const int srow = tid >> 3, ssl = tid & 7;
  const unsigned char* ga = sM8 + (size_t)(rowBase + srow) * D_DIM + ((ssl ^ (srow & 7)) * 16);
  const int bRow0 = wn * 64 + l15;
  f32x4 acc[8][4] = {};
  mainloopBG(ga, xte8h, As, wm * 128 + l15, colBase + bRow0, lhi, tid, acc);
  __syncthreads();

  float* snlds = reinterpret_cast<float*>(As);     // [256]
  if (tid < 256) snlds[tid] = sn2[rowBase + tid];
  __syncthreads();
  float cn[4];
#pragma unroll
  for (int n = 0; n < 4; ++n) cn[n] = cn2h[colBase + bRow0 + n * 16];
#pragma unroll
  for (int m = 0; m < 8; ++m) {
#pragma unroll
    for (int r = 0; r < 4; ++r) {
      const int lrow = wm * 128 + m * 16 + lhi * 4 + r;
      const float sn = snlds[lrow];
      const size_t grow = rowBase + lrow;
#pragma unroll
      for (int n = 0; n < 4; ++n) {
        float d2 = sn + cn[n] - 2.f * acc[m][n][r];
        float kv = exp2f(-0.14426950408889634f * sqrtf(fmaxf(d2, 0.f)));
        S[grow * 4096 + colBase + bRow0 + n * 16] = f2bf(kv);
      }
    }
  }
}

// ---- k_out: column-wise weighted reduction of one half of S -> part ----
__global__ __launch_bounds__(256) void k_out(const unsigned short* __restrict__ S,
                                             const float* __restrict__ Y,
                                             float* __restrict__ part, int halfBase) {
  __shared__ float ylds[256 * 10];
  const int tid = threadIdx.x;
  const int sBase = blockIdx.y * 256;
  const int tloc = blockIdx.x * 256 + tid;       // 0..4095
  const int tglob = halfBase + tloc;
  for (int i = tid; i < 2560; i += 256) ylds[i] = Y[(size_t)sBase * 10 + i];
  __syncthreads();
  float num[10] = {0, 0, 0, 0, 0, 0, 0, 0, 0, 0};
  float den = 0.f;
  for (int s = 0; s < 256; ++s) {
    float kv = bf2f(S[(size_t)(sBase + s) * 4096 + tloc]);
    const float* yr = &ylds[s * 10];
#pragma unroll
    for (int c = 0; c < 10; ++c) num[c] += kv * yr[c];
    den += kv;
  }
#pragma unroll
  for (int c = 0; c < 10; ++c)
    part[((size_t)blockIdx.y * 11 + c) * NTEST + tglob] = num[c];
  part[((size_t)blockIdx.y * 11 + 10) * NTEST + tglob] = den;
}

// ---------------- final reduce ----------------
__global__ void k_reduce(const float* __restrict__ part, float* __restrict__ out) {
  int t = blockIdx.x * blockDim.x + threadIdx.x;
  float num[10] = {0, 0, 0, 0, 0, 0, 0, 0, 0, 0};
  float den = 0.f;
  for (int it = 0; it < NTRAIN / 256; ++it) {
    const float* p = part + (size_t)it * 11 * NTEST + t;
#pragma unroll
    for (int c = 0; c < 10; ++c) num[c] += p[(size_t)c * NTEST];
    den += p[(size_t)10 * NTEST];
  }
  float inv = 1.f / den;
#pragma unroll
  for (int c = 0; c < 10; ++c) out[(size_t)t * 10 + c] = num[c] * inv;
}

extern "C" void kernel_launch(void* const* d_in, const int* in_sizes, int n_in,
                              void* d_out, int out_size, void* d_ws, size_t ws_size,
                              hipStream_t stream) {
  const float* x_train = (const float*)d_in[0];
  const float* y_train = (const float*)d_in[1];
  const float* x_test  = (const float*)d_in[2];
  const float* M       = (const float*)d_in[3];
  float* out = (float*)d_out;

  char* ws = (char*)d_ws;
  unsigned char*  xtr8 = (unsigned char*)(ws + 0);            // 50331648
  unsigned char*  xte8 = (unsigned char*)(ws + 50331648);     // 25165824
  unsigned char*  Mt8  = (unsigned char*)(ws + 75497472);     // 9437184
  unsigned char*  sM8  = (unsigned char*)(ws + 84934656);     // 50331648
  float* s_n2 = (float*)(ws + 135266304);                     // 65536
  float* c_n2 = (float*)(ws + 135331840);                     // 32768
  float* part = (float*)(ws + 135364608);                     // 23068672
  unsigned short* S = (unsigned short*)(ws + 158433280);      // 134217728

  hipMemsetAsync(ws + 135266304, 0, 98304, stream);  // s_n2 + c_n2

  k_convert8<<<1024, 256, 0, stream>>>(x_train, xtr8, (long)NTRAIN * D_DIM / 8);
  k_convert8<<<1024, 256, 0, stream>>>(x_test, xte8, (long)NTEST * D_DIM / 8);
  k_transpose_fp8<<<dim3(96, 96), dim3(32, 8), 0, stream>>>(M, Mt8);
  k_copy4<<<2048, 256, 0, stream>>>((const float4*)M, (float4*)(out + 81920),
                                    (long)D_DIM * D_DIM / 4);

  k_gemm_xm8<true><<<dim3(12, 64), 512, 0, stream>>>(xtr8, Mt8, x_train, sM8, s_n2);
  k_gemm_xm8<false><<<dim3(12, 32), 512, 0, stream>>>(xte8, Mt8, x_test, nullptr, c_n2);

  for (int h = 0; h < 2; ++h) {
    k_gemm_cross<<<dim3(16, 64), 512, 0, stream>>>(
        sM8, xte8 + (size_t)h * 4096 * D_DIM, s_n2, c_n2 + h * 4096, S);
    k_out<<<dim3(16, 64), 256, 0, stream>>>(S, y_train, part, h * 4096);
  }
  k_reduce<<<32, 256, 0, stream>>>(part, out);
}

// Round 23
// 1365.693 us; speedup vs baseline: 1.8714x; 1.8714x over previous
//
#include <hip/hip_runtime.h>
#include <hip/hip_bf16.h>

#define D_DIM 3072
#define NTRAIN 16384
#define NTEST 8192

typedef __attribute__((ext_vector_type(4))) float f32x4;
typedef __attribute__((ext_vector_type(4))) int i32x4;
typedef __attribute__((ext_vector_type(8))) int i32x8;

__device__ __forceinline__ unsigned short f2bf(float f) {
  union { float f; unsigned u; } x; x.f = f;
  unsigned r = x.u + 0x7FFFu + ((x.u >> 16) & 1u);
  return (unsigned short)(r >> 16);
}

__device__ __forceinline__ float bf2f(unsigned short b) {
  union { unsigned u; float f; } x; x.u = ((unsigned)b) << 16;
  return x.f;
}

__device__ __forceinline__ i32x8 cmb(i32x4 lo, i32x4 hi) {
  i32x8 r;
  r[0] = lo[0]; r[1] = lo[1]; r[2] = lo[2]; r[3] = lo[3];
  r[4] = hi[0]; r[5] = hi[1]; r[6] = hi[2]; r[7] = hi[3];
  return r;
}

__device__ __forceinline__ void gload16(const void* g, void* l) {
  __builtin_amdgcn_global_load_lds(
      (const __attribute__((address_space(1))) void*)g,
      (__attribute__((address_space(3))) void*)l, 16, 0, 0);
}

// T1a: bijective chunked XCD swizzle + 8x8 supertile (needs gx%8==0, gy%8==0).
__device__ __forceinline__ void swz_tile(int& tileY, int& tileX) {
  const int gx = gridDim.x, gy = gridDim.y;
  const int L = blockIdx.y * gx + blockIdx.x;
  const int q = (gx * gy) >> 3;
  const int s = (L & 7) * q + (L >> 3);
  const int sid = s >> 6;
  const int t = s & 63;
  const int scols = gx >> 3;
  const int sy = sid / scols, sx = sid - sy * scols;
  tileY = sy * 8 + (t >> 3);
  tileX = sx * 8 + (t & 7);
}

// T1b: plain bijective chunked swizzle (needs nwg%8==0 only).
__device__ __forceinline__ void swz_lin(int& tileY, int& tileX) {
  const int gx = gridDim.x;
  const int nwg = gx * gridDim.y;
  const int L = blockIdx.y * gx + blockIdx.x;
  const int s = (L & 7) * (nwg >> 3) + (L >> 3);
  tileY = s / gx;
  tileX = s - tileY * gx;
}

// ---------------- pass 0 ----------------
__global__ void k_convert8(const float* __restrict__ in, unsigned char* __restrict__ out, long n8) {
  long i = (long)blockIdx.x * blockDim.x + threadIdx.x;
  long stride = (long)gridDim.x * blockDim.x;
  for (; i < n8; i += stride) {
    float4 a = reinterpret_cast<const float4*>(in)[i * 2];
    float4 b = reinterpret_cast<const float4*>(in)[i * 2 + 1];
    int w0 = __builtin_amdgcn_cvt_pk_fp8_f32(a.x, a.y, 0, false);
    w0 = __builtin_amdgcn_cvt_pk_fp8_f32(a.z, a.w, w0, true);
    int w1 = __builtin_amdgcn_cvt_pk_fp8_f32(b.x, b.y, 0, false);
    w1 = __builtin_amdgcn_cvt_pk_fp8_f32(b.z, b.w, w1, true);
    reinterpret_cast<int2*>(out)[i] = make_int2(w0, w1);
  }
}

__global__ void k_copy4(const float4* __restrict__ in, float4* __restrict__ out, long n4) {
  long i = (long)blockIdx.x * blockDim.x + threadIdx.x;
  long stride = (long)gridDim.x * blockDim.x;
  for (; i < n4; i += stride) out[i] = in[i];
}

// Mt8[n][k] = fp8(M[k][n])
__global__ void k_transpose_fp8(const float* __restrict__ M, unsigned char* __restrict__ Mt) {
  __shared__ float t[32][33];
  int bx = blockIdx.x * 32, by = blockIdx.y * 32;
  int tx = threadIdx.x, ty = threadIdx.y;
#pragma unroll
  for (int i = 0; i < 32; i += 8)
    t[ty + i][tx] = M[(size_t)(by + ty + i) * D_DIM + bx + tx];
  __syncthreads();
#pragma unroll
  for (int i = 0; i < 32; i += 8) {
    float v = t[tx][ty + i];
    int p = __builtin_amdgcn_cvt_pk_fp8_f32(v, v, 0, false);
    Mt[(size_t)(bx + ty + i) * D_DIM + by + tx] = (unsigned char)(p & 0xFF);
  }
}

// ======== shared MX-fp8 mainloop: 256x256, BK=128, A in LDS, B from global ========
// 8 waves (2M x 4N), wave tile 128x64, acc[8][4]=128 regs (AGPR). A-only LDS
// (64 KiB dbuf, XOR layout, 0-conflict): LDS unit load/CU/tile drops 192->128
// b128 (2304->1536 cy < MFMA 2200 cy — LDS ceases to be the pole). B (2x reuse
// only) is loaded global->VGPR fresh each tile (TRANSIENT b8[4]; no ping-pong,
// no persistent row pointers — R22's spill cause). Its ~200cy L2 latency hides
// under the first q-group's ds_reads + sibling wave. One sync per tile.
// mfma_scale_f32_16x16x128_f8f6f4 unit scales = exact fp8 math at 2x rate.
__device__ __forceinline__ void mainloopBG(const unsigned char* __restrict__ ga,
                                           const unsigned char* __restrict__ gBrow,
                                           unsigned char* As,
                                           int aRow0, int lhi, int tid,
                                           f32x4 acc[8][4]) {
  const int nt = D_DIM / 128;                    // 24
  const int g0 = lhi, g1 = lhi ^ 4;
  // prologue: stage A(0)
#pragma unroll
  for (int j = 0; j < 4; ++j)
    gload16(ga + (size_t)j * 64 * D_DIM, As + j * 8192 + tid * 16);

#define RDA(Ac, q, H)                                                                \
  cmb(*reinterpret_cast<const i32x4*>(                                               \
          &(Ac)[(aRow0 + (q) * 32 + (H) * 16) * 128 +                                \
                ((g0 ^ ((aRow0 + (q) * 32 + (H) * 16) & 7)) * 16)]),                 \
      *reinterpret_cast<const i32x4*>(                                               \
          &(Ac)[(aRow0 + (q) * 32 + (H) * 16) * 128 +                                \
                ((g1 ^ ((aRow0 + (q) * 32 + (H) * 16) & 7)) * 16)]))

  for (int t = 0; t < nt; ++t) {
    const int p = t & 1;
    const unsigned char* Ac = As + p * 32768;
    unsigned char* An = As + (p ^ 1) * 32768;
    asm volatile("s_waitcnt vmcnt(0)" ::: "memory");   // A(t) staged (B(t-1) long consumed)
    __builtin_amdgcn_s_barrier();
    __builtin_amdgcn_sched_barrier(0);
    if (t + 1 < nt) {
      const int k1 = (t + 1) * 128;
#pragma unroll
      for (int j = 0; j < 4; ++j)
        gload16(ga + (size_t)j * 64 * D_DIM + k1, An + j * 8192 + tid * 16);
    }
    // B operands for THIS tile: transient regs, loaded from global (L2)
    const unsigned char* pB = gBrow + (size_t)t * 128;
    i32x8 b8[4];
#pragma unroll
    for (int n = 0; n < 4; ++n)
      b8[n] = cmb(*reinterpret_cast<const i32x4*>(pB + (size_t)n * 16 * D_DIM + g0 * 16),
                  *reinterpret_cast<const i32x4*>(pB + (size_t)n * 16 * D_DIM + g1 * 16));
    __builtin_amdgcn_sched_barrier(0);
#pragma unroll
    for (int q = 0; q < 4; ++q) {
      i32x8 a0 = RDA(Ac, q, 0), a1 = RDA(Ac, q, 1);
      __builtin_amdgcn_s_setprio(1);
#pragma unroll
      for (int n = 0; n < 4; ++n) {
        acc[q * 2][n] = __builtin_amdgcn_mfma_scale_f32_16x16x128_f8f6f4(
            a0, b8[n], acc[q * 2][n], 0, 0, 0, 127, 0, 127);
        acc[q * 2 + 1][n] = __builtin_amdgcn_mfma_scale_f32_16x16x128_f8f6f4(
            a1, b8[n], acc[q * 2 + 1][n], 0, 0, 0, 127, 0, 127);
      }
      __builtin_amdgcn_s_setprio(0);
      __builtin_amdgcn_sched_barrier(0);
    }
  }
#undef RDA
}

// ---- GEMM1: X @ M, MX-fp8. Epilogue: norm2 dot vs f32 X (+ optional sM8) ----
template <bool WRITE_SM>
__global__ __launch_bounds__(512, 2) void k_gemm_xm8(const unsigned char* __restrict__ X8,
                                                     const unsigned char* __restrict__ Mt8,
                                                     const float* __restrict__ Xf,
                                                     unsigned char* __restrict__ smOut,
                                                     float* __restrict__ norm) {
  __shared__ unsigned char As[2 * 256 * 128];    // 64 KiB, A only
  const int tid = threadIdx.x, lane = tid & 63, wave = tid >> 6;
  const int wm = wave >> 2, wn = wave & 3;       // 2M x 4N
  const int l15 = lane & 15, lhi = lane >> 4;
  int tileY, tileX;
  swz_lin(tileY, tileX);
  const int rowBase = tileY * 256, colBase = tileX * 256;
  const int srow = tid >> 3, ssl = tid & 7;
  const unsigned char* ga = X8 + (size_t)(rowBase + srow) * D_DIM + ((ssl ^ (srow & 7)) * 16);
  const unsigned char* gBrow = Mt8 + (size_t)(colBase + wn * 64 + l15) * D_DIM;
  f32x4 acc[8][4] = {};
  mainloopBG(ga, gBrow, As, wm * 128 + l15, lhi, tid, acc);
  __syncthreads();

  const int c0 = colBase + wn * 64 + l15;
#pragma unroll
  for (int m = 0; m < 8; ++m) {
#pragma unroll
    for (int r = 0; r < 4; ++r) {
      const size_t grow = rowBase + wm * 128 + m * 16 + lhi * 4 + r;
      float v = 0.f;
#pragma unroll
      for (int n = 0; n < 4; ++n) {
        float a = acc[m][n][r];
        const int gcol = c0 + n * 16;
        v += a * Xf[grow * D_DIM + gcol];
        if (WRITE_SM) {
          int pk = __builtin_amdgcn_cvt_pk_fp8_f32(a, a, 0, false);
          smOut[grow * D_DIM + gcol] = (unsigned char)(pk & 0xFF);
        }
      }
      v += __shfl_xor(v, 1); v += __shfl_xor(v, 2);
      v += __shfl_xor(v, 4); v += __shfl_xor(v, 8);
      if ((lane & 15) == 0) atomicAdd(&norm[grow], v);
    }
  }
}

// ---- GEMM2: MX-fp8, STORE-ONLY epilogue -> bf16 S half ----
__global__ __launch_bounds__(512, 2) void k_gemm_cross(const unsigned char* __restrict__ sM8,
                                                       const unsigned char* __restrict__ xte8h,
                                                       const float* __restrict__ sn2,
                                                       const float* __restrict__ cn2h,
                                                       unsigned short* __restrict__ S) {
  __shared__ unsigned char As[2 * 256 * 128];    // 64 KiB, A only
  const int tid = threadIdx.x, lane = tid & 63, wave = tid >> 6;
  const int wm = wave >> 2, wn = wave & 3;
  const int l15 = lane & 15, lhi = lane >> 4;
  int tileY, tileX;
  swz_tile(tileY, tileX);
  const int rowBase = tileY * 256, colBase = tileX * 256;
  const int srow = tid >> 3, ssl = tid & 7;
  const unsigned char* ga = sM8 + (size_t)(rowBase + srow) * D_DIM + ((ssl ^ (srow & 7)) * 16);
  const int bRow0 = wn * 64 + l15;
  const unsigned char* gBrow = xte8h + (size_t)(colBase + bRow0) * D_DIM;
  f32x4 acc[8][4] = {};
  mainloopBG(ga, gBrow, As, wm * 128 + l15, lhi, tid, acc);
  __syncthreads();

  float* snlds = reinterpret_cast<float*>(As);     // [256]
  if (tid < 256) snlds[tid] = sn2[rowBase + tid];
  __syncthreads();
  float cn[4];
#pragma unroll
  for (int n = 0; n < 4; ++n) cn[n] = cn2h[colBase + bRow0 + n * 16];
#pragma unroll
  for (int m = 0; m < 8; ++m) {
#pragma unroll
    for (int r = 0; r < 4; ++r) {
      const int lrow = wm * 128 + m * 16 + lhi * 4 + r;
      const float sn = snlds[lrow];
      const size_t grow = rowBase + lrow;
#pragma unroll
      for (int n = 0; n < 4; ++n) {
        float d2 = sn + cn[n] - 2.f * acc[m][n][r];
        float kv = exp2f(-0.14426950408889634f * sqrtf(fmaxf(d2, 0.f)));
        S[grow * 4096 + colBase + bRow0 + n * 16] = f2bf(kv);
      }
    }
  }
}

// ---- k_out: column-wise weighted reduction of one half of S -> part ----
__global__ __launch_bounds__(256) void k_out(const unsigned short* __restrict__ S,
                                             const float* __restrict__ Y,
                                             float* __restrict__ part, int halfBase) {
  __shared__ float ylds[256 * 10];
  const int tid = threadIdx.x;
  const int sBase = blockIdx.y * 256;
  const int tloc = blockIdx.x * 256 + tid;       // 0..4095
  const int tglob = halfBase + tloc;
  for (int i = tid; i < 2560; i += 256) ylds[i] = Y[(size_t)sBase * 10 + i];
  __syncthreads();
  float num[10] = {0, 0, 0, 0, 0, 0, 0, 0, 0, 0};
  float den = 0.f;
  for (int s = 0; s < 256; ++s) {
    float kv = bf2f(S[(size_t)(sBase + s) * 4096 + tloc]);
    const float* yr = &ylds[s * 10];
#pragma unroll
    for (int c = 0; c < 10; ++c) num[c] += kv * yr[c];
    den += kv;
  }
#pragma unroll
  for (int c = 0; c < 10; ++c)
    part[((size_t)blockIdx.y * 11 + c) * NTEST + tglob] = num[c];
  part[((size_t)blockIdx.y * 11 + 10) * NTEST + tglob] = den;
}

// ---------------- final reduce ----------------
__global__ void k_reduce(const float* __restrict__ part, float* __restrict__ out) {
  int t = blockIdx.x * blockDim.x + threadIdx.x;
  float num[10] = {0, 0, 0, 0, 0, 0, 0, 0, 0, 0};
  float den = 0.f;
  for (int it = 0; it < NTRAIN / 256; ++it) {
    const float* p = part + (size_t)it * 11 * NTEST + t;
#pragma unroll
    for (int c = 0; c < 10; ++c) num[c] += p[(size_t)c * NTEST];
    den += p[(size_t)10 * NTEST];
  }
  float inv = 1.f / den;
#pragma unroll
  for (int c = 0; c < 10; ++c) out[(size_t)t * 10 + c] = num[c] * inv;
}

extern "C" void kernel_launch(void* const* d_in, const int* in_sizes, int n_in,
                              void* d_out, int out_size, void* d_ws, size_t ws_size,
                              hipStream_t stream) {
  const float* x_train = (const float*)d_in[0];
  const float* y_train = (const float*)d_in[1];
  const float* x_test  = (const float*)d_in[2];
  const float* M       = (const float*)d_in[3];
  float* out = (float*)d_out;

  char* ws = (char*)d_ws;
  unsigned char*  xtr8 = (unsigned char*)(ws + 0);            // 50331648
  unsigned char*  xte8 = (unsigned char*)(ws + 50331648);     // 25165824
  unsigned char*  Mt8  = (unsigned char*)(ws + 75497472);     // 9437184
  unsigned char*  sM8  = (unsigned char*)(ws + 84934656);     // 50331648
  float* s_n2 = (float*)(ws + 135266304);                     // 65536
  float* c_n2 = (float*)(ws + 135331840);                     // 32768
  float* part = (float*)(ws + 135364608);                     // 23068672
  unsigned short* S = (unsigned short*)(ws + 158433280);      // 134217728

  hipMemsetAsync(ws + 135266304, 0, 98304, stream);  // s_n2 + c_n2

  k_convert8<<<1024, 256, 0, stream>>>(x_train, xtr8, (long)NTRAIN * D_DIM / 8);
  k_convert8<<<1024, 256, 0, stream>>>(x_test, xte8, (long)NTEST * D_DIM / 8);
  k_transpose_fp8<<<dim3(96, 96), dim3(32, 8), 0, stream>>>(M, Mt8);
  k_copy4<<<2048, 256, 0, stream>>>((const float4*)M, (float4*)(out + 81920),
                                    (long)D_DIM * D_DIM / 4);

  k_gemm_xm8<true><<<dim3(12, 64), 512, 0, stream>>>(xtr8, Mt8, x_train, sM8, s_n2);
  k_gemm_xm8<false><<<dim3(12, 32), 512, 0, stream>>>(xte8, Mt8, x_test, nullptr, c_n2);

  for (int h = 0; h < 2; ++h) {
    k_gemm_cross<<<dim3(16, 64), 512, 0, stream>>>(
        sM8, xte8 + (size_t)h * 4096 * D_DIM, s_n2, c_n2 + h * 4096, S);
    k_out<<<dim3(16, 64), 256, 0, stream>>>(S, y_train, part, h * 4096);
  }
  k_reduce<<<32, 256, 0, stream>>>(part, out);
}